// Round 13
// baseline (1587.972 us; speedup 1.0000x reference)
//
#include <hip/hip_runtime.h>
#include <hip/hip_bf16.h>

#define B_ 16
#define L_ 96
#define N_ 1024
#define EMB_ 64

typedef __hip_bfloat16 bf16;
typedef __attribute__((ext_vector_type(4))) float f32x4;
typedef __attribute__((ext_vector_type(8))) short s16x8;

// ================= fp32 GEMM (NN), small setup mats =================
// MODE 0: plain. MODE 1: qk batch — blockIdx.z = z*2+which.
template <int MODE>
__global__ __launch_bounds__(256) void gemm_nn(
    const float* __restrict__ A, const float* __restrict__ Bm, float* __restrict__ C,
    int M, int N, int K, int lda, int ldb, int ldc, const float* __restrict__ bias)
{
    if (MODE == 1) {
        const int bz = blockIdx.z, z = bz >> 1;
        A += (size_t)z * 65536;
        const float* Wsel = (bz & 1) ? (const float*)bias : Bm;
        Bm = Wsel + z * 4096;
        C += (size_t)bz * 65536;
        bias = nullptr;
    }
    __shared__ float As[64][17];
    __shared__ __align__(16) float Bs[16][64];
    const int tid = threadIdx.x;
    const int tx = tid & 15, ty = tid >> 4;
    const int row0 = blockIdx.y * 64, col0 = blockIdx.x * 64;
    float acc[4][4] = {};
    const int ak = tid & 15, ar = tid >> 4;
    const int bc = tid & 63, bk = tid >> 6;
    for (int k0 = 0; k0 < K; k0 += 16) {
#pragma unroll
        for (int i = 0; i < 4; ++i) {
            int r = ar + i * 16;
            int gr = row0 + r, gk = k0 + ak;
            As[r][ak] = (gr < M && gk < K) ? A[(size_t)gr * lda + gk] : 0.f;
        }
#pragma unroll
        for (int i = 0; i < 4; ++i) {
            int kk = bk + i * 4;
            int gk = k0 + kk, gc = col0 + bc;
            Bs[kk][bc] = (gk < K && gc < N) ? Bm[(size_t)gk * ldb + gc] : 0.f;
        }
        __syncthreads();
#pragma unroll
        for (int kk = 0; kk < 16; ++kk) {
            float4 b4 = *reinterpret_cast<const float4*>(&Bs[kk][tx * 4]);
            float a0 = As[ty * 4 + 0][kk];
            float a1 = As[ty * 4 + 1][kk];
            float a2 = As[ty * 4 + 2][kk];
            float a3 = As[ty * 4 + 3][kk];
            acc[0][0] += a0 * b4.x; acc[0][1] += a0 * b4.y; acc[0][2] += a0 * b4.z; acc[0][3] += a0 * b4.w;
            acc[1][0] += a1 * b4.x; acc[1][1] += a1 * b4.y; acc[1][2] += a1 * b4.z; acc[1][3] += a1 * b4.w;
            acc[2][0] += a2 * b4.x; acc[2][1] += a2 * b4.y; acc[2][2] += a2 * b4.z; acc[2][3] += a2 * b4.w;
            acc[3][0] += a3 * b4.x; acc[3][1] += a3 * b4.y; acc[3][2] += a3 * b4.z; acc[3][3] += a3 * b4.w;
        }
        __syncthreads();
    }
#pragma unroll
    for (int i = 0; i < 4; ++i) {
        int gr = row0 + ty * 4 + i;
        if (gr >= M) continue;
#pragma unroll
        for (int j = 0; j < 4; ++j) {
            int gc = col0 + tx * 4 + j;
            if (gc >= N) continue;
            float v = acc[i][j];
            if (bias) v += bias[gc];
            C[(size_t)gr * ldc + gc] = v;
        }
    }
}

// ================= fp32 GEMM (NT), z-batched via blockIdx.z =================
__global__ __launch_bounds__(256) void gemm_nt(
    const float* __restrict__ A, const float* __restrict__ Bm, float* __restrict__ C,
    int N, int K, float alpha, int zsA, int zsB, int zsC)
{
    const int z = blockIdx.z;
    A += (size_t)z * zsA; Bm += (size_t)z * zsB; C += (size_t)z * zsC;
    __shared__ float As[64][65];
    __shared__ float Bs[64][65];
    const int tid = threadIdx.x;
    const int row0 = blockIdx.y * 64, col0 = blockIdx.x * 64;
    for (int idx = tid; idx < 64 * K; idx += 256) {
        int r = idx / K, c = idx % K;
        As[r][c] = A[(size_t)(row0 + r) * K + c];
        Bs[r][c] = Bm[(size_t)(col0 + r) * K + c];
    }
    __syncthreads();
    const int tx = tid & 15, ty = tid >> 4;
    float acc[4][4] = {};
    for (int c = 0; c < K; ++c) {
        float a[4], b[4];
#pragma unroll
        for (int i = 0; i < 4; ++i) a[i] = As[ty * 4 + i][c];
#pragma unroll
        for (int j = 0; j < 4; ++j) b[j] = Bs[tx * 4 + j][c];
#pragma unroll
        for (int i = 0; i < 4; ++i)
#pragma unroll
            for (int j = 0; j < 4; ++j) acc[i][j] += a[i] * b[j];
    }
#pragma unroll
    for (int i = 0; i < 4; ++i)
#pragma unroll
        for (int j = 0; j < 4; ++j)
            C[(size_t)(row0 + ty * 4 + i) * N + col0 + tx * 4 + j] = alpha * acc[i][j];
}

// ======= row softmax over 1024 cols, z-batched (blockIdx.y) =======
__global__ __launch_bounds__(256) void row_softmax(
    const float* __restrict__ in, float* __restrict__ out32, int os32,
    bf16* __restrict__ out16, int os16, int zs_in, int zs16, int relu)
{
    const int z = blockIdx.y;
    const float* rp = in + (size_t)z * zs_in + (size_t)blockIdx.x * N_;
    if (out32) out32 += (size_t)z * zs_in;
    if (out16) out16 += (size_t)z * zs16;
    const int tid = threadIdx.x;
    float v[4];
#pragma unroll
    for (int j = 0; j < 4; ++j) {
        float x = rp[tid + 256 * j];
        if (relu) x = fmaxf(x, 0.f);
        v[j] = x;
    }
    float m = fmaxf(fmaxf(v[0], v[1]), fmaxf(v[2], v[3]));
#pragma unroll
    for (int off = 32; off > 0; off >>= 1) m = fmaxf(m, __shfl_xor(m, off));
    __shared__ float red[4], red2[4];
    int w = tid >> 6;
    if ((tid & 63) == 0) red[w] = m;
    __syncthreads();
    m = fmaxf(fmaxf(red[0], red[1]), fmaxf(red[2], red[3]));
    float s = 0.f;
#pragma unroll
    for (int j = 0; j < 4; ++j) { v[j] = __expf(v[j] - m); s += v[j]; }
#pragma unroll
    for (int off = 32; off > 0; off >>= 1) s += __shfl_xor(s, off);
    if ((tid & 63) == 0) red2[w] = s;
    __syncthreads();
    s = red2[0] + red2[1] + red2[2] + red2[3];
    float inv = 1.f / s;
#pragma unroll
    for (int j = 0; j < 4; ++j) {
        float r = v[j] * inv;
        if (out32) out32[(size_t)blockIdx.x * os32 + tid + 256 * j] = r;
        if (out16) out16[(size_t)blockIdx.x * os16 + tid + 256 * j] = __float2bfloat16(r);
    }
}

// ======= transpose 1024x1024 fp32 -> bf16, z-batched =======
__global__ __launch_bounds__(256) void transpose_f2b(
    const float* __restrict__ in, bf16* __restrict__ out)
{
    const int z = blockIdx.z;
    in += (size_t)z * 1048576; out += (size_t)z * 1048576;
    __shared__ float t[64][65];
    const int cx = blockIdx.x, cy = blockIdx.y;
    const int tid = threadIdx.x;
#pragma unroll
    for (int k = 0; k < 16; ++k) {
        int idx = k * 256 + tid;
        int r = idx >> 6, c = idx & 63;
        t[r][c] = in[(size_t)(cy * 64 + r) * 1024 + cx * 64 + c];
    }
    __syncthreads();
#pragma unroll
    for (int k = 0; k < 16; ++k) {
        int idx = k * 256 + tid;
        int r = idx >> 6, c = idx & 63;
        out[(size_t)(cx * 64 + r) * 1024 + cy * 64 + c] = __float2bfloat16(t[c][r]);
    }
}

// ================= WgcT[(g*64+f)][e] = Wg[g][e][f], bf16 =================
__global__ __launch_bounds__(256) void wgct_kernel(const float* __restrict__ Wg,
                                                   bf16* __restrict__ WgcT)
{
    int i = blockIdx.x * 256 + threadIdx.x;  // 16384
    int g = i >> 12, e = (i >> 6) & 63, f = i & 63;
    WgcT[(((size_t)g * 64 + f) << 6) + e] = __float2bfloat16(Wg[i]);
}

// ====== Wvc1T[(kp*64+e)][f] = Wvc1[kp][f][e], bf16, padded to 256 rows ======
__global__ __launch_bounds__(256) void wvc1t_kernel(const float* __restrict__ Wvc1,
                                                    bf16* __restrict__ WT)
{
    int i = blockIdx.x * 256 + threadIdx.x;  // 256*64
    int row = i >> 6, f = i & 63;
    float v = 0.f;
    if (row < 192) { int kp = row >> 6, e = row & 63; v = Wvc1[kp * 4096 + f * 64 + e]; }
    WT[i] = __float2bfloat16(v);
}

// ================= fp32 -> bf16 convert =================
__global__ __launch_bounds__(256) void f2b_kernel(const float* __restrict__ in,
                                                  bf16* __restrict__ out, int n)
{
    int i = blockIdx.x * 256 + threadIdx.x;
    if (i < n) out[i] = __float2bfloat16(in[i]);
}

// ================= folded gate bias =================
__global__ __launch_bounds__(256) void bias_kernel(
    const float* __restrict__ bvz, const float* __restrict__ Wmz, const float* __restrict__ bmz,
    const float* __restrict__ Wgz, const float* __restrict__ bgz, float* __restrict__ bgconst)
{
    __shared__ float bconst[64];
    const int tid = threadIdx.x;
    if (tid < 64) {
        float s = bmz[tid];
        for (int kp = 0; kp < 3; ++kp)
            for (int f = 0; f < 64; ++f) s += bvz[f] * Wmz[kp * 4096 + f * 64 + tid];
        bconst[tid] = s;
    }
    __syncthreads();
    int g = tid >> 6, fo = tid & 63;
    float s = bgz[g * 64 + fo];
    for (int e = 0; e < 64; ++e) s += bconst[e] * Wgz[g * 4096 + e * 64 + fo];
    bgconst[tid] = s;
}

// ====== WbigT[(g*64+f)][q] = sum_e Wvc0[kp][c][e]*Wg0[g][e][f], q=kp*3+c, pad 32 ======
__global__ __launch_bounds__(256) void wbig_kernel(
    const float* __restrict__ Wvc0, const float* __restrict__ Wg0, bf16* __restrict__ WbigT)
{
    const int tid = threadIdx.x;
    const int g = tid >> 6, fo = tid & 63;
    float v[9];
#pragma unroll
    for (int q = 0; q < 9; ++q) {
        const int kp = q / 3, c = q % 3;
        float s = 0.f;
        for (int e = 0; e < 64; ++e)
            s += Wvc0[kp * 192 + c * 64 + e] * Wg0[g * 4096 + e * 64 + fo];
        v[q] = s;
    }
#pragma unroll
    for (int i = 0; i < 32; ++i)
        WbigT[(size_t)tid * 32 + i] = __float2bfloat16(i < 9 ? v[i] : 0.f);
}

// ====== XT[(lglobal*16+b)*3+c][n] = hist[b][l][n][c], bf16 — whole run ======
__global__ __launch_bounds__(256) void xt_build(
    const float* __restrict__ hist, bf16* __restrict__ XT)
{
    __shared__ float xs[3][1024];
    const int lb = blockIdx.x;   // l*16+b, l global 0..95
    const int l = lb >> 4, b = lb & 15;
    const int tid = threadIdx.x;
    const float* xp = hist + ((size_t)b * L_ + l) * N_ * 3;
    for (int i = tid; i < 3072; i += 256) xs[i % 3][i / 3] = xp[i];
    __syncthreads();
#pragma unroll
    for (int c = 0; c < 3; ++c)
#pragma unroll
        for (int q = 0; q < 4; ++q) {
            int n = q * 256 + tid;
            XT[((size_t)lb * 3 + c) * 1024 + n] = __float2bfloat16(xs[c][n]);
        }
}

__device__ __forceinline__ void gload16(const bf16* g, bf16* l)
{
    __builtin_amdgcn_global_load_lds((const __attribute__((address_space(1))) void*)g,
                                     (__attribute__((address_space(3))) void*)l, 16, 0, 0);
}

// ================= bf16 MFMA GEMM (NT): C = A @ BT^T, 128^2 tile =================
// REMAP=1: layer-1 V scatter into VcatT.  REMAP=2: Y scatter (A += z*1024 K-offset).
// REMAP=3: merged M1/M2 for both layers — blockIdx.z = z*2+which.
template <int OUT_BF16, int REMAP>
__global__ __launch_bounds__(256) void gemm_mfma(
    const bf16* __restrict__ A, const bf16* __restrict__ BT, void* __restrict__ Cp,
    int M, int N, int K, int lda, int ldb, int ldc,
    const float* __restrict__ bias, int Nmask)
{
    __shared__ __align__(16) bf16 As[128 * 64];
    __shared__ __align__(16) bf16 Bs[128 * 64];
    const int tid = threadIdx.x;
    const int lane = tid & 63, w = tid >> 6;
    const int wr = w >> 1, wc = w & 1;
    const int row0 = blockIdx.y * 128, col0 = blockIdx.x * 128;
    if (REMAP == 1) BT += (size_t)blockIdx.z * 64;
    if (REMAP == 2) A += (size_t)blockIdx.z * 1024;
    if (REMAP == 3) {
        const int z3 = blockIdx.z >> 1, wh = blockIdx.z & 1;
        if (wh) A = BT + (size_t)z3 * 1048576;                       // adp_z
        BT = (const bf16*)bias + (size_t)z3 * 1048576;               // attnT_z
        Cp = (void*)((bf16*)Cp + (size_t)z3 * 3145728 + (size_t)wh * 1024);
        bias = nullptr;
    }

    f32x4 acc[4][4];
#pragma unroll
    for (int i = 0; i < 4; ++i)
#pragma unroll
        for (int j = 0; j < 4; ++j) acc[i][j] = (f32x4){0.f, 0.f, 0.f, 0.f};

    const int srow = w * 32 + (lane >> 3);
    const int scolsw = ((lane & 7) ^ (lane >> 3)) * 8;

    for (int k0 = 0; k0 < K; k0 += 64) {
#pragma unroll
        for (int i = 0; i < 4; ++i) {
            gload16(A + (size_t)(row0 + srow + i * 8) * lda + k0 + scolsw,
                    &As[(w * 32 + i * 8) * 64]);
            gload16(BT + (size_t)(col0 + srow + i * 8) * ldb + k0 + scolsw,
                    &Bs[(w * 32 + i * 8) * 64]);
        }
        __syncthreads();
#pragma unroll
        for (int kk = 0; kk < 64; kk += 32) {
            s16x8 af[4], bfr[4];
            const int ko = (kk + (lane >> 4) * 8) ^ ((lane & 7) << 3);
#pragma unroll
            for (int mi = 0; mi < 4; ++mi)
                af[mi] = *(const s16x8*)&As[(wr * 64 + mi * 16 + (lane & 15)) * 64 + ko];
#pragma unroll
            for (int ni = 0; ni < 4; ++ni)
                bfr[ni] = *(const s16x8*)&Bs[(wc * 64 + ni * 16 + (lane & 15)) * 64 + ko];
#pragma unroll
            for (int mi = 0; mi < 4; ++mi)
#pragma unroll
                for (int ni = 0; ni < 4; ++ni)
                    acc[mi][ni] = __builtin_amdgcn_mfma_f32_16x16x32_bf16(
                        af[mi], bfr[ni], acc[mi][ni], 0, 0, 0);
        }
        __syncthreads();
    }

    if (REMAP == 1) {
        bf16* outb = (bf16*)Cp + (size_t)blockIdx.z * (64 * 3072);
#pragma unroll
        for (int mi = 0; mi < 4; ++mi) {
            const int gr = row0 + wr * 64 + mi * 16 + (lane >> 4) * 4;
#pragma unroll
            for (int ni = 0; ni < 4; ++ni) {
                const int gc = col0 + wc * 64 + ni * 16 + (lane & 15);
#pragma unroll
                for (int j = 0; j < 4; ++j) {
                    const int r = gr + j;
                    if (r >= Nmask) continue;
                    outb[(size_t)(r & 63) * 3072 + (r >> 6) * 1024 + gc] =
                        __float2bfloat16(acc[mi][ni][j]);
                }
            }
        }
        return;
    }
    if (REMAP == 2) {
        bf16* outb = (bf16*)Cp;
        const int kpoff = blockIdx.z * 3;
#pragma unroll
        for (int mi = 0; mi < 4; ++mi) {
            const int gr = row0 + wr * 64 + mi * 16 + (lane >> 4) * 4;
#pragma unroll
            for (int ni = 0; ni < 4; ++ni) {
                const int gc = col0 + wc * 64 + ni * 16 + (lane & 15);
                if (gc >= Nmask) continue;
                const int dstc = (gc / 3) * 32 + kpoff + gc % 3;
#pragma unroll
                for (int j = 0; j < 4; ++j)
                    outb[(size_t)(gr + j) * ldc + dstc] = __float2bfloat16(acc[mi][ni][j]);
            }
        }
        return;
    }

#pragma unroll
    for (int mi = 0; mi < 4; ++mi) {
        const int gr = row0 + wr * 64 + mi * 16 + (lane >> 4) * 4;
#pragma unroll
        for (int ni = 0; ni < 4; ++ni) {
            const int gc = col0 + wc * 64 + ni * 16 + (lane & 15);
            if (gc >= Nmask) continue;
            const float bb = bias ? bias[gc] : 0.f;
#pragma unroll
            for (int j = 0; j < 4; ++j) {
                float v = acc[mi][ni][j] + bb;
                if (OUT_BF16)
                    ((bf16*)Cp)[(size_t)(gr + j) * ldc + gc] = __float2bfloat16(v);
                else
                    ((float*)Cp)[(size_t)(gr + j) * ldc + gc] = v;
            }
        }
    }
}

// ====== 8-phase pipelined bf16 MFMA GEMM (NT), 256x256 tile, BK=64 (r7-validated) ======
// C = A @ BT^T; Nc = C row stride (>= grid.x*256); col range written = [0, grid.x*256).
__global__ __launch_bounds__(512) void gemm_pipe(
    const bf16* __restrict__ A, const bf16* __restrict__ BT, bf16* __restrict__ C,
    int Nc, int K)
{
    __shared__ __align__(16) bf16 lds[8 * 8192];
    const int tid = threadIdx.x;
    const int lane = tid & 63, w = tid >> 6;
    const int wm = w >> 2, wn = w & 3, bh = wn >> 1;
    const int row0 = blockIdx.y * 256, col0 = blockIdx.x * 256;

    const int strow = tid >> 3;
    const int srck  = ((tid & 7) ^ ((tid >> 3) & 7)) << 3;
    const int e7 = lane & 7, fs = lane >> 4, a15 = lane & 15;

    int aoff0[8], boff0[4];
#pragma unroll
    for (int mi = 0; mi < 8; ++mi)
        aoff0[mi] = (mi * 16 + a15) * 64 + ((fs ^ e7) << 3);
#pragma unroll
    for (int ni = 0; ni < 4; ++ni)
        boff0[ni] = ((wn & 1) * 64 + ni * 16 + a15) * 64 + ((fs ^ e7) << 3);

    auto stage = [&](int mat, int half, int kt) {
        bf16* dst = &lds[(size_t)((((kt & 1) << 1) | mat) * 2 + half) * 8192 + w * 512];
        const bf16* src = (mat ? BT + (size_t)col0 * K : A + (size_t)row0 * K)
                          + (size_t)(half * 128) * K + kt * 64 + srck;
        gload16(src + (size_t)strow * K, dst);
        gload16(src + (size_t)(64 + strow) * K, dst + 4096);
    };

    f32x4 acc[8][4];
#pragma unroll
    for (int i = 0; i < 8; ++i)
#pragma unroll
        for (int j = 0; j < 4; ++j) acc[i][j] = (f32x4){0.f, 0.f, 0.f, 0.f};

    s16x8 b0, b1, b2, b3;

#define MF_(a, mi) { \
    acc[mi][0] = __builtin_amdgcn_mfma_f32_16x16x32_bf16(a, b0, acc[mi][0], 0, 0, 0); \
    acc[mi][1] = __builtin_amdgcn_mfma_f32_16x16x32_bf16(a, b1, acc[mi][1], 0, 0, 0); \
    acc[mi][2] = __builtin_amdgcn_mfma_f32_16x16x32_bf16(a, b2, acc[mi][2], 0, 0, 0); \
    acc[mi][3] = __builtin_amdgcn_mfma_f32_16x16x32_bf16(a, b3, acc[mi][3], 0, 0, 0); }

#define PH_(d, kh, g, DOB, STG) { \
    const bf16* Ab = &lds[((d) * 4 + wm) * 8192]; \
    const bf16* Bb = &lds[((d) * 4 + 2 + bh) * 8192]; \
    if (DOB) { \
        b0 = *(const s16x8*)&Bb[boff0[0] ^ ((kh) * 32)]; \
        b1 = *(const s16x8*)&Bb[boff0[1] ^ ((kh) * 32)]; \
        b2 = *(const s16x8*)&Bb[boff0[2] ^ ((kh) * 32)]; \
        b3 = *(const s16x8*)&Bb[boff0[3] ^ ((kh) * 32)]; \
    } \
    s16x8 a0 = *(const s16x8*)&Ab[aoff0[(g) * 4 + 0] ^ ((kh) * 32)]; \
    s16x8 a1 = *(const s16x8*)&Ab[aoff0[(g) * 4 + 1] ^ ((kh) * 32)]; \
    s16x8 a2 = *(const s16x8*)&Ab[aoff0[(g) * 4 + 2] ^ ((kh) * 32)]; \
    s16x8 a3 = *(const s16x8*)&Ab[aoff0[(g) * 4 + 3] ^ ((kh) * 32)]; \
    STG; \
    __builtin_amdgcn_s_barrier(); \
    asm volatile("s_waitcnt lgkmcnt(0)" ::: "memory"); \
    __builtin_amdgcn_sched_barrier(0); \
    __builtin_amdgcn_s_setprio(1); \
    MF_(a0, (g) * 4 + 0); MF_(a1, (g) * 4 + 1); \
    MF_(a2, (g) * 4 + 2); MF_(a3, (g) * 4 + 3); \
    __builtin_amdgcn_s_setprio(0); \
    __builtin_amdgcn_s_barrier(); }

    const int NT = K >> 6;   // even
    stage(0, 0, 0); stage(0, 1, 0); stage(1, 0, 0); stage(1, 1, 0);
    stage(0, 0, 1);

    for (int i = 0; i < NT / 2; ++i) {
        const int kt = 2 * i;
        asm volatile("s_waitcnt vmcnt(2)" ::: "memory");
        __builtin_amdgcn_sched_barrier(0);
        __builtin_amdgcn_s_barrier();
        PH_(0, 0, 0, 1, { stage(0, 1, kt + 1); });
        PH_(0, 0, 1, 0, { stage(1, 0, kt + 1); });
        PH_(0, 1, 0, 1, { stage(1, 1, kt + 1); });
        PH_(0, 1, 1, 0, { if (kt + 2 < NT) stage(0, 0, kt + 2); });
        if (kt + 2 < NT) { asm volatile("s_waitcnt vmcnt(2)" ::: "memory"); }
        else             { asm volatile("s_waitcnt vmcnt(0)" ::: "memory"); }
        __builtin_amdgcn_sched_barrier(0);
        __builtin_amdgcn_s_barrier();
        PH_(1, 0, 0, 1, { if (kt + 2 < NT) stage(0, 1, kt + 2); });
        PH_(1, 0, 1, 0, { if (kt + 2 < NT) stage(1, 0, kt + 2); });
        PH_(1, 1, 0, 1, { if (kt + 2 < NT) stage(1, 1, kt + 2); });
        PH_(1, 1, 1, 0, { if (kt + 3 < NT) stage(0, 0, kt + 3); });
    }
#undef PH_
#undef MF_

#pragma unroll
    for (int mi = 0; mi < 8; ++mi) {
        const int gr = row0 + wm * 128 + mi * 16 + (lane >> 4) * 4;
#pragma unroll
        for (int ni = 0; ni < 4; ++ni) {
            const int gc = col0 + wn * 64 + ni * 16 + (lane & 15);
#pragma unroll
            for (int j = 0; j < 4; ++j)
                C[(size_t)(gr + j) * Nc + gc] = __float2bfloat16(acc[mi][ni][j]);
        }
    }
}

// ========== layer-1: fused gates GEMM (K=64) + IN-REGISTER LSTM scan ==========
__global__ __launch_bounds__(256, 4) void fused_gates_scan(
    const bf16* __restrict__ HG, const bf16* __restrict__ WgcT,
    const float* __restrict__ bgc, float* __restrict__ ct_buf,
    bf16* __restrict__ ht_out, float* __restrict__ htlast,
    int LC, int l0, int initct)
{
    __shared__ __align__(16) bf16 Bs[256 * 64];
    __shared__ float bgs[256];
    const int tid = threadIdx.x;
    const int lane = tid & 63, w = tid >> 6;
    const int n = blockIdx.x;
    const int swz = ((lane & 7) ^ (lane >> 3)) * 8;
    const int l8 = (lane >> 3) * 64;

#pragma unroll
    for (int r = 0; r < 8; ++r)
        gload16(WgcT + r * 2048 + w * 512 + l8 + swz, &Bs[r * 2048 + w * 512]);
    bgs[tid] = bgc[tid];
    __syncthreads();

    const int ar = lane & 15;
    const int ak = (lane >> 4) * 8;
    const int kswz = (lane & 7) << 3;
    const int f = w * 16 + ar;
    const int r0 = (lane >> 4) * 4;
    const float bgf = bgs[f], bgi = bgs[64 + f], bgg = bgs[128 + f], bgo = bgs[192 + f];

    float ct[4];
    const size_t cbase = (size_t)n * 1024;
#pragma unroll
    for (int j = 0; j < 4; ++j)
        ct[j] = initct ? 0.f : ct_buf[cbase + (size_t)(r0 + j) * 64 + f];

    const bf16* HGn = HG + (size_t)n * LC * 1024;
    s16x8 a0 = *(const s16x8*)&HGn[ar * 64 + ak];
    s16x8 a1 = *(const s16x8*)&HGn[ar * 64 + ak + 32];

    for (int l = 0; l < LC; ++l) {
        s16x8 p0 = a0, p1 = a1;
        if (l + 1 < LC) {
            p0 = *(const s16x8*)&HGn[((l + 1) * 16 + ar) * 64 + ak];
            p1 = *(const s16x8*)&HGn[((l + 1) * 16 + ar) * 64 + ak + 32];
        }
        f32x4 acc[4];
#pragma unroll
        for (int ni = 0; ni < 4; ++ni) acc[ni] = (f32x4){0.f, 0.f, 0.f, 0.f};
#pragma unroll
        for (int ni = 0; ni < 4; ++ni) {
            s16x8 bf = *(const s16x8*)&Bs[(ni * 64 + w * 16 + ar) * 64 + (ak ^ kswz)];
            acc[ni] = __builtin_amdgcn_mfma_f32_16x16x32_bf16(a0, bf, acc[ni], 0, 0, 0);
        }
#pragma unroll
        for (int ni = 0; ni < 4; ++ni) {
            s16x8 bf = *(const s16x8*)&Bs[(ni * 64 + w * 16 + ar) * 64 + ((ak + 32) ^ kswz)];
            acc[ni] = __builtin_amdgcn_mfma_f32_16x16x32_bf16(a1, bf, acc[ni], 0, 0, 0);
        }
        const size_t hbase = ((size_t)n * LC + l) * 1024;
        const bool last = (l0 + l == L_ - 1);
#pragma unroll
        for (int j = 0; j < 4; ++j) {
            float xf = acc[0][j] + bgf;
            float xi = acc[1][j] + bgi;
            float xg = acc[2][j] + bgg;
            float xo = acc[3][j] + bgo;
            float fg = 1.f / (1.f + __expf(-xf));
            float ig = 1.f / (1.f + __expf(-xi));
            float gg = 2.f / (1.f + __expf(-2.f * xg)) - 1.f;
            float og = 1.f / (1.f + __expf(-xo));
            ct[j] = fg * ct[j] + ig * gg;
            float ht = og * (2.f / (1.f + __expf(-2.f * ct[j])) - 1.f);
            if (ht_out) ht_out[hbase + (size_t)(r0 + j) * 64 + f] = __float2bfloat16(ht);
            if (htlast && last) htlast[cbase + (size_t)(r0 + j) * 64 + f] = ht;
        }
        a0 = p0; a1 = p1;
    }
#pragma unroll
    for (int j = 0; j < 4; ++j)
        ct_buf[cbase + (size_t)(r0 + j) * 64 + f] = ct[j];
}

// ========== layer-0: gates from Y (K=32, rank-9) + IN-REGISTER LSTM scan ==========
__global__ __launch_bounds__(256, 4) void fused_gates_scan_y(
    const bf16* __restrict__ Y, const bf16* __restrict__ WbigT,
    const float* __restrict__ bgc, float* __restrict__ ct_buf,
    bf16* __restrict__ ht_out, float* __restrict__ htlast,
    int LC, int l0, int initct)
{
    __shared__ bf16 Bs2[256 * 40];
    __shared__ float bgs[256];
    const int tid = threadIdx.x;
    const int lane = tid & 63, w = tid >> 6;
    const int n = blockIdx.x;
    {
        const uint4* src = (const uint4*)(WbigT + (size_t)tid * 32);
        uint4* dst = (uint4*)&Bs2[tid * 40];
        dst[0] = src[0]; dst[1] = src[1]; dst[2] = src[2]; dst[3] = src[3];
    }
    bgs[tid] = bgc[tid];
    __syncthreads();

    const int ar = lane & 15, fs = lane >> 4;
    const int f = w * 16 + ar;
    const int r0 = fs * 4;
    const float bgf = bgs[f], bgi = bgs[64 + f], bgg = bgs[128 + f], bgo = bgs[192 + f];

    float ct[4];
    const size_t cbase = (size_t)n * 1024;
#pragma unroll
    for (int j = 0; j < 4; ++j)
        ct[j] = initct ? 0.f : ct_buf[cbase + (size_t)(r0 + j) * 64 + f];

    const bf16* Yn = Y + (size_t)n * LC * 512;
    s16x8 a = *(const s16x8*)&Yn[ar * 32 + fs * 8];

    for (int l = 0; l < LC; ++l) {
        s16x8 p = a;
        if (l + 1 < LC) p = *(const s16x8*)&Yn[((l + 1) * 16 + ar) * 32 + fs * 8];
        f32x4 acc[4];
#pragma unroll
        for (int ni = 0; ni < 4; ++ni) {
            s16x8 bf = *(const s16x8*)&Bs2[(ni * 64 + w * 16 + ar) * 40 + fs * 8];
            acc[ni] = __builtin_amdgcn_mfma_f32_16x16x32_bf16(
                a, bf, (f32x4){0.f, 0.f, 0.f, 0.f}, 0, 0, 0);
        }
        const size_t hbase = ((size_t)n * LC + l) * 1024;
        const bool last = (l0 + l == L_ - 1);
#pragma unroll
        for (int j = 0; j < 4; ++j) {
            float xf = acc[0][j] + bgf;
            float xi = acc[1][j] + bgi;
            float xg = acc[2][j] + bgg;
            float xo = acc[3][j] + bgo;
            float fg = 1.f / (1.f + __expf(-xf));
            float ig = 1.f / (1.f + __expf(-xi));
            float gg = 2.f / (1.f + __expf(-2.f * xg)) - 1.f;
            float og = 1.f / (1.f + __expf(-xo));
            ct[j] = fg * ct[j] + ig * gg;
            float ht = og * (2.f / (1.f + __expf(-2.f * ct[j])) - 1.f);
            if (ht_out) ht_out[hbase + (size_t)(r0 + j) * 64 + f] = __float2bfloat16(ht);
            if (htlast && last) htlast[cbase + (size_t)(r0 + j) * 64 + f] = ht;
        }
        a = p;
    }
#pragma unroll
    for (int j = 0; j < 4; ++j)
        ct_buf[cbase + (size_t)(r0 + j) * 64 + f] = ct[j];
}

// ================= decoder =================
__global__ __launch_bounds__(256) void decoder_kernel(
    const float* __restrict__ h0, const float* __restrict__ h1,
    const float* __restrict__ Wdec, const float* __restrict__ bdec,
    const float* __restrict__ Wout, const float* __restrict__ bout,
    float* __restrict__ outp)
{
    __shared__ float Wd[12 * 2 * 64];
    __shared__ float Wo[144];
    __shared__ float bd[12], bo[12];
    const int tid = threadIdx.x;
    for (int i = tid; i < 12 * 2 * 64; i += 256) Wd[i] = Wdec[i];
    for (int i = tid; i < 144; i += 256) Wo[i] = Wout[i];
    if (tid < 12) { bd[tid] = bdec[tid]; bo[tid] = bout[tid]; }
    __syncthreads();
    const int gid = blockIdx.x * 256 + tid;   // b*1024 + n
    const int b = gid >> 10, n = gid & 1023;
    const float* h0r = h0 + ((size_t)n * 16 + b) * 64;
    const float* h1r = h1 + ((size_t)n * 16 + b) * 64;
    float dec[12];
#pragma unroll
    for (int o = 0; o < 12; ++o) dec[o] = bd[o];
    for (int e = 0; e < 64; ++e) {
        float v0 = h0r[e], v1 = h1r[e];
#pragma unroll
        for (int o = 0; o < 12; ++o) dec[o] += v0 * Wd[o * 128 + e] + v1 * Wd[o * 128 + 64 + e];
    }
#pragma unroll
    for (int o = 0; o < 12; ++o) {
        float s = bo[o];
#pragma unroll
        for (int p = 0; p < 12; ++p) s += Wo[o * 12 + p] * dec[p];
        outp[((size_t)b * 12 + o) * 1024 + n] = s;
    }
}

extern "C" void kernel_launch(void* const* d_in, const int* in_sizes, int n_in,
                              void* d_out, int out_size, void* d_ws, size_t ws_size,
                              hipStream_t stream)
{
    const float* hist = (const float*)d_in[0];
    const float* adj  = (const float*)d_in[1];
    const float* Wv0  = (const float*)d_in[2];
    const float* Wv1  = (const float*)d_in[3];
    const float* bv   = (const float*)d_in[4];
    const float* E    = (const float*)d_in[5];
    const float* Wq   = (const float*)d_in[6];
    const float* Wk   = (const float*)d_in[7];
    const float* Eg1  = (const float*)d_in[8];
    const float* Eg2  = (const float*)d_in[9];
    const float* Wmix = (const float*)d_in[10];
    const float* bmix = (const float*)d_in[11];
    const float* Wg   = (const float*)d_in[12];
    const float* bg   = (const float*)d_in[13];
    const float* Wdec = (const float*)d_in[14];
    const float* bdec = (const float*)d_in[15];
    const float* Wout = (const float*)d_in[16];
    const float* bout = (const float*)d_in[17];
    float* outp = (float*)d_out;
    (void)in_sizes; (void)n_in; (void)out_size;

    char* ws = (char*)d_ws;
    size_t off = 0;
    auto alloc = [&](size_t bytes) -> void* {
        void* p = (void*)(ws + off);
        off += (bytes + 255) & ~(size_t)255;
        return p;
    };
    bf16*  Mcatb  = (bf16*)alloc((size_t)2 * 1024 * 3072 * 2);  // z-contiguous
    bf16*  attnT2 = (bf16*)alloc((size_t)2 * 1024 * 1024 * 2);  // per-z
    bf16*  adjb   = (bf16*)alloc((size_t)1024 * 1024 * 2);
    bf16*  adpb2  = (bf16*)alloc((size_t)2 * 1024 * 1024 * 2);  // per-z
    float* qkb    = (float*)alloc((size_t)4 * 1024 * 64 * 4);   // [z][q|k]
    float* logit2 = (float*)alloc((size_t)2 * 1024 * 1024 * 4); // per-z, in-place softmax
    float* Wvc0   = (float*)alloc(3 * 3 * 64 * 4);
    float* Wvc1   = (float*)alloc(3 * 64 * 64 * 4);
    bf16*  Wvc1T  = (bf16*)alloc(256 * 64 * 2);
    bf16*  WgcT1  = (bf16*)alloc(256 * 64 * 2);
    bf16*  WbigT  = (bf16*)alloc(256 * 32 * 2);
    float* bgc0   = (float*)alloc(256 * 4);
    float* bgc1   = (float*)alloc(256 * 4);
    float* ct0    = (float*)alloc((size_t)N_ * B_ * 64 * 4);
    float* ct1    = (float*)alloc((size_t)N_ * B_ * 64 * 4);
    float* hl0    = (float*)alloc((size_t)N_ * B_ * 64 * 4);
    float* hl1    = (float*)alloc((size_t)N_ * B_ * 64 * 4);
    bf16*  XT     = (bf16*)alloc((size_t)L_ * 16 * 3 * 1024 * 2);  // 9.4MB
    size_t fixed = off;

    // ---- plan selection by workspace size ----
    const size_t YALL_B = (size_t)1024 * L_ * 16 * 32 * 2;   // 96MB
    const size_t HT_B   = (size_t)1024 * L_ * 16 * 64 * 2;   // 192MB
    const size_t GUARD  = 1 << 20;
    int plan;  int LC;
    if (fixed + YALL_B + HT_B + (size_t)16 * 6291456ull + HT_B + GUARD <= ws_size) {
        plan = 0; LC = 16;                 // full-L layer0 + unified HG + single layer1 scan
    } else if (fixed + YALL_B + HT_B + (size_t)16 * 6291456ull
               + (size_t)16 * 2097152ull + GUARD <= ws_size) {
        plan = 1; LC = 16;                 // full-L layer0, per-chunk layer1
    } else if (fixed + (size_t)16 * 9437184ull + GUARD <= ws_size) {
        plan = 2; LC = 16;                 // r12 path
    } else {
        plan = 2; LC = 8;
    }

    bf16 *Yall = nullptr, *ht0 = nullptr, *VcatT = nullptr, *HG = nullptr, *Ychunk = nullptr;
    if (plan <= 1) {
        Yall  = (bf16*)alloc(YALL_B);
        ht0   = (bf16*)alloc(HT_B);
        VcatT = (bf16*)alloc((size_t)LC * 6291456ull);
        HG    = (bf16*)alloc(plan == 0 ? HT_B : (size_t)LC * 2097152ull);
    } else {
        VcatT  = (bf16*)alloc((size_t)LC * 6291456ull);
        HG     = (bf16*)alloc((size_t)LC * 2097152ull);   // HG / ht0c aliased
        Ychunk = (bf16*)alloc((size_t)LC * 1048576ull);
    }

    dim3 blk(256);
    dim3 blk512(512);
    bf16*  McatB[2] = {Mcatb, Mcatb + 3145728};

    // -------- setup, z-batched --------
    f2b_kernel<<<4096, blk, 0, stream>>>(adj, adjb, 1024 * 1024);
    gemm_nn<1><<<dim3(1, 16, 4), blk, 0, stream>>>(E, Wq, qkb,
        1024, 64, 64, 64, 64, 64, (const float*)Wk);
    gemm_nt<<<dim3(16, 16, 2), blk, 0, stream>>>(qkb, qkb + 65536, logit2,
        1024, 64, 0.125f, 131072, 131072, 1048576);
    row_softmax<<<dim3(1024, 2), blk, 0, stream>>>(logit2, logit2, 1024,
        Mcatb + 2048, 3072, 1048576, 3145728, 0);
    transpose_f2b<<<dim3(16, 16, 2), blk, 0, stream>>>(logit2, attnT2);
    gemm_nt<<<dim3(16, 16, 2), blk, 0, stream>>>(Eg1, Eg2, logit2,
        1024, 16, 1.f, 16384, 16384, 1048576);
    row_softmax<<<dim3(1024, 2), blk, 0, stream>>>(logit2, nullptr, 0,
        adpb2, 1024, 1048576, 1048576, 1);
    for (int kp = 0; kp < 3; ++kp)
        gemm_nn<0><<<dim3(1, 1), blk, 0, stream>>>(Wv0, Wmix + kp * 4096,
            Wvc0 + kp * 3 * 64, 3, 64, 64, 64, 64, 64, nullptr);
    wbig_kernel<<<1, blk, 0, stream>>>(Wvc0, Wg, WbigT);
    for (int kp = 0; kp < 3; ++kp)
        gemm_nn<0><<<dim3(1, 1), blk, 0, stream>>>(Wv1, Wmix + 12288 + kp * 4096,
            Wvc1 + kp * 4096, 64, 64, 64, 64, 64, 64, nullptr);
    wvc1t_kernel<<<64, blk, 0, stream>>>(Wvc1, Wvc1T);
    wgct_kernel<<<64, blk, 0, stream>>>(Wg + 16384, WgcT1);
    bias_kernel<<<1, blk, 0, stream>>>(bv, Wmix, bmix, Wg, bg, bgc0);
    bias_kernel<<<1, blk, 0, stream>>>(bv + 64, Wmix + 12288, bmix + 64,
        Wg + 16384, bg + 256, bgc1);
    gemm_mfma<1, 3><<<dim3(8, 8, 4), blk, 0, stream>>>(adjb, adpb2, Mcatb,
        1024, 1024, 1024, 1024, 1024, 3072, (const float*)attnT2, 1024);

    xt_build<<<L_ * 16, blk, 0, stream>>>(hist, XT);

    if (plan <= 1) {
        // ---- layer 0 over ALL 96 steps in two launches ----
        hipMemsetAsync(Yall, 0, YALL_B, stream);
        gemm_mfma<1, 2><<<dim3(L_ * 48 / 128, 8, 3), blk, 0, stream>>>(McatB[0],
            XT, Yall, 1024, L_ * 48, 1024, 3072, 1024, L_ * 512, nullptr, L_ * 48);
        fused_gates_scan_y<<<1024, blk, 0, stream>>>(Yall, WbigT, bgc0, ct0,
            ht0, hl0, L_, 0, 1);
        // ---- layer 1 ----
        const int nch = L_ / LC;
        for (int c = 0; c < nch; ++c) {
            const int l0 = c * LC;
            gemm_mfma<1, 1><<<dim3(8, 2, LC * 16), blk, 0, stream>>>(Wvc1T,
                ht0 + (size_t)l0 * 1024, VcatT,
                256, 1024, 64, 64, L_ * 1024, 0, nullptr, 192);
            if (plan == 0) {
                gemm_pipe<<<dim3(LC * 4, 4), blk512, 0, stream>>>(McatB[1], VcatT,
                    HG + (size_t)l0 * 1024, L_ * 1024, 3072);
            } else {
                gemm_pipe<<<dim3(LC * 4, 4), blk512, 0, stream>>>(McatB[1], VcatT,
                    HG, LC * 1024, 3072);
                fused_gates_scan<<<1024, blk, 0, stream>>>(HG, WgcT1, bgc1, ct1,
                    nullptr, hl1, LC, l0, c == 0);
            }
        }
        if (plan == 0)
            fused_gates_scan<<<1024, blk, 0, stream>>>(HG, WgcT1, bgc1, ct1,
                nullptr, hl1, L_, 0, 1);
    } else {
        // ---- r12 per-chunk path ----
        hipMemsetAsync(Ychunk, 0, (size_t)LC * 1048576ull, stream);
        const int nch = L_ / LC;
        for (int c = 0; c < nch; ++c) {
            const int l0 = c * LC;
            gemm_mfma<1, 2><<<dim3(LC * 48 / 128, 8, 3), blk, 0, stream>>>(McatB[0],
                XT + (size_t)l0 * 49152, Ychunk,
                1024, LC * 48, 1024, 3072, 1024, LC * 512, nullptr, LC * 48);
            fused_gates_scan_y<<<1024, blk, 0, stream>>>(Ychunk, WbigT, bgc0, ct0,
                HG, hl0, LC, l0, c == 0);
            gemm_mfma<1, 1><<<dim3(8, 2, LC * 16), blk, 0, stream>>>(Wvc1T, HG, VcatT,
                256, 1024, 64, 64, LC * 1024, 0, nullptr, 192);
            gemm_pipe<<<dim3(LC * 4, 4), blk512, 0, stream>>>(McatB[1], VcatT, HG,
                LC * 1024, 3072);
            fused_gates_scan<<<1024, blk, 0, stream>>>(HG, WgcT1, bgc1, ct1,
                nullptr, hl1, LC, l0, c == 0);
        }
    }
    decoder_kernel<<<64, blk, 0, stream>>>(hl0, hl1, Wdec, bdec, Wout, bout, outp);
}

// Round 14
// 1536.679 us; speedup vs baseline: 1.0334x; 1.0334x over previous
//
#include <hip/hip_runtime.h>
#include <hip/hip_bf16.h>

#define B_ 16
#define L_ 96
#define N_ 1024
#define EMB_ 64

typedef __hip_bfloat16 bf16;
typedef __attribute__((ext_vector_type(4))) float f32x4;
typedef __attribute__((ext_vector_type(8))) short s16x8;

// ================= fp32 GEMM (NN), small setup mats =================
// MODE 0: plain. MODE 1: qk batch (blockIdx.z = z*2+which).
// MODE 2: merged tiny weight GEMMs — blockIdx.z = t in [0,6): kp=t%3;
//   t<3: A=Wv0(M=3), B=Wmix+kp*4096, C=Cbase+kp*192;
//   t>=3: A=Wv1(=bias cast, M=64), B=Wmix+12288+kp*4096, C=Cbase+640+kp*4096.
template <int MODE>
__global__ __launch_bounds__(256) void gemm_nn(
    const float* __restrict__ A, const float* __restrict__ Bm, float* __restrict__ C,
    int M, int N, int K, int lda, int ldb, int ldc, const float* __restrict__ bias)
{
    if (MODE == 1) {
        const int bz = blockIdx.z, z = bz >> 1;
        A += (size_t)z * 65536;
        const float* Wsel = (bz & 1) ? (const float*)bias : Bm;
        Bm = Wsel + z * 4096;
        C += (size_t)bz * 65536;
        bias = nullptr;
    }
    if (MODE == 2) {
        const int t = blockIdx.z, kp = t % 3;
        if (t < 3) { M = 3;  Bm += kp * 4096;          C += kp * 192; }
        else       { M = 64; A = (const float*)bias;   Bm += 12288 + kp * 4096;
                     C += 640 + kp * 4096; }
        bias = nullptr;
    }
    __shared__ float As[64][17];
    __shared__ __align__(16) float Bs[16][64];
    const int tid = threadIdx.x;
    const int tx = tid & 15, ty = tid >> 4;
    const int row0 = blockIdx.y * 64, col0 = blockIdx.x * 64;
    float acc[4][4] = {};
    const int ak = tid & 15, ar = tid >> 4;
    const int bc = tid & 63, bk = tid >> 6;
    for (int k0 = 0; k0 < K; k0 += 16) {
#pragma unroll
        for (int i = 0; i < 4; ++i) {
            int r = ar + i * 16;
            int gr = row0 + r, gk = k0 + ak;
            As[r][ak] = (gr < M && gk < K) ? A[(size_t)gr * lda + gk] : 0.f;
        }
#pragma unroll
        for (int i = 0; i < 4; ++i) {
            int kk = bk + i * 4;
            int gk = k0 + kk, gc = col0 + bc;
            Bs[kk][bc] = (gk < K && gc < N) ? Bm[(size_t)gk * ldb + gc] : 0.f;
        }
        __syncthreads();
#pragma unroll
        for (int kk = 0; kk < 16; ++kk) {
            float4 b4 = *reinterpret_cast<const float4*>(&Bs[kk][tx * 4]);
            float a0 = As[ty * 4 + 0][kk];
            float a1 = As[ty * 4 + 1][kk];
            float a2 = As[ty * 4 + 2][kk];
            float a3 = As[ty * 4 + 3][kk];
            acc[0][0] += a0 * b4.x; acc[0][1] += a0 * b4.y; acc[0][2] += a0 * b4.z; acc[0][3] += a0 * b4.w;
            acc[1][0] += a1 * b4.x; acc[1][1] += a1 * b4.y; acc[1][2] += a1 * b4.z; acc[1][3] += a1 * b4.w;
            acc[2][0] += a2 * b4.x; acc[2][1] += a2 * b4.y; acc[2][2] += a2 * b4.z; acc[2][3] += a2 * b4.w;
            acc[3][0] += a3 * b4.x; acc[3][1] += a3 * b4.y; acc[3][2] += a3 * b4.z; acc[3][3] += a3 * b4.w;
        }
        __syncthreads();
    }
#pragma unroll
    for (int i = 0; i < 4; ++i) {
        int gr = row0 + ty * 4 + i;
        if (gr >= M) continue;
#pragma unroll
        for (int j = 0; j < 4; ++j) {
            int gc = col0 + tx * 4 + j;
            if (gc >= N) continue;
            float v = acc[i][j];
            if (bias && MODE == 0) v += bias[gc];
            C[(size_t)gr * ldc + gc] = v;
        }
    }
}

// ================= fp32 GEMM (NT), z-batched via blockIdx.z =================
__global__ __launch_bounds__(256) void gemm_nt(
    const float* __restrict__ A, const float* __restrict__ Bm, float* __restrict__ C,
    int N, int K, float alpha, int zsA, int zsB, int zsC)
{
    const int z = blockIdx.z;
    A += (size_t)z * zsA; Bm += (size_t)z * zsB; C += (size_t)z * zsC;
    __shared__ float As[64][65];
    __shared__ float Bs[64][65];
    const int tid = threadIdx.x;
    const int row0 = blockIdx.y * 64, col0 = blockIdx.x * 64;
    for (int idx = tid; idx < 64 * K; idx += 256) {
        int r = idx / K, c = idx % K;
        As[r][c] = A[(size_t)(row0 + r) * K + c];
        Bs[r][c] = Bm[(size_t)(col0 + r) * K + c];
    }
    __syncthreads();
    const int tx = tid & 15, ty = tid >> 4;
    float acc[4][4] = {};
    for (int c = 0; c < K; ++c) {
        float a[4], b[4];
#pragma unroll
        for (int i = 0; i < 4; ++i) a[i] = As[ty * 4 + i][c];
#pragma unroll
        for (int j = 0; j < 4; ++j) b[j] = Bs[tx * 4 + j][c];
#pragma unroll
        for (int i = 0; i < 4; ++i)
#pragma unroll
            for (int j = 0; j < 4; ++j) acc[i][j] += a[i] * b[j];
    }
#pragma unroll
    for (int i = 0; i < 4; ++i)
#pragma unroll
        for (int j = 0; j < 4; ++j)
            C[(size_t)(row0 + ty * 4 + i) * N + col0 + tx * 4 + j] = alpha * acc[i][j];
}

// ======= row softmax over 1024 cols, z-batched (blockIdx.y) =======
__global__ __launch_bounds__(256) void row_softmax(
    const float* __restrict__ in, float* __restrict__ out32, int os32,
    bf16* __restrict__ out16, int os16, int zs_in, int zs16, int relu)
{
    const int z = blockIdx.y;
    const float* rp = in + (size_t)z * zs_in + (size_t)blockIdx.x * N_;
    if (out32) out32 += (size_t)z * zs_in;
    if (out16) out16 += (size_t)z * zs16;
    const int tid = threadIdx.x;
    float v[4];
#pragma unroll
    for (int j = 0; j < 4; ++j) {
        float x = rp[tid + 256 * j];
        if (relu) x = fmaxf(x, 0.f);
        v[j] = x;
    }
    float m = fmaxf(fmaxf(v[0], v[1]), fmaxf(v[2], v[3]));
#pragma unroll
    for (int off = 32; off > 0; off >>= 1) m = fmaxf(m, __shfl_xor(m, off));
    __shared__ float red[4], red2[4];
    int w = tid >> 6;
    if ((tid & 63) == 0) red[w] = m;
    __syncthreads();
    m = fmaxf(fmaxf(red[0], red[1]), fmaxf(red[2], red[3]));
    float s = 0.f;
#pragma unroll
    for (int j = 0; j < 4; ++j) { v[j] = __expf(v[j] - m); s += v[j]; }
#pragma unroll
    for (int off = 32; off > 0; off >>= 1) s += __shfl_xor(s, off);
    if ((tid & 63) == 0) red2[w] = s;
    __syncthreads();
    s = red2[0] + red2[1] + red2[2] + red2[3];
    float inv = 1.f / s;
#pragma unroll
    for (int j = 0; j < 4; ++j) {
        float r = v[j] * inv;
        if (out32) out32[(size_t)blockIdx.x * os32 + tid + 256 * j] = r;
        if (out16) out16[(size_t)blockIdx.x * os16 + tid + 256 * j] = __float2bfloat16(r);
    }
}

// ======= transpose 1024x1024 fp32 -> bf16, z-batched =======
__global__ __launch_bounds__(256) void transpose_f2b(
    const float* __restrict__ in, bf16* __restrict__ out)
{
    const int z = blockIdx.z;
    in += (size_t)z * 1048576; out += (size_t)z * 1048576;
    __shared__ float t[64][65];
    const int cx = blockIdx.x, cy = blockIdx.y;
    const int tid = threadIdx.x;
#pragma unroll
    for (int k = 0; k < 16; ++k) {
        int idx = k * 256 + tid;
        int r = idx >> 6, c = idx & 63;
        t[r][c] = in[(size_t)(cy * 64 + r) * 1024 + cx * 64 + c];
    }
    __syncthreads();
#pragma unroll
    for (int k = 0; k < 16; ++k) {
        int idx = k * 256 + tid;
        int r = idx >> 6, c = idx & 63;
        out[(size_t)(cx * 64 + r) * 1024 + cy * 64 + c] = __float2bfloat16(t[c][r]);
    }
}

// ================= WgcT[(g*64+f)][e] = Wg[g][e][f], bf16 =================
__global__ __launch_bounds__(256) void wgct_kernel(const float* __restrict__ Wg,
                                                   bf16* __restrict__ WgcT)
{
    int i = blockIdx.x * 256 + threadIdx.x;  // 16384
    int g = i >> 12, e = (i >> 6) & 63, f = i & 63;
    WgcT[(((size_t)g * 64 + f) << 6) + e] = __float2bfloat16(Wg[i]);
}

// ====== Wvc1T[(kp*64+e)][f] = Wvc1[kp][f][e], bf16, padded to 256 rows ======
__global__ __launch_bounds__(256) void wvc1t_kernel(const float* __restrict__ Wvc1,
                                                    bf16* __restrict__ WT)
{
    int i = blockIdx.x * 256 + threadIdx.x;  // 256*64
    int row = i >> 6, f = i & 63;
    float v = 0.f;
    if (row < 192) { int kp = row >> 6, e = row & 63; v = Wvc1[kp * 4096 + f * 64 + e]; }
    WT[i] = __float2bfloat16(v);
}

// ================= fp32 -> bf16 convert =================
__global__ __launch_bounds__(256) void f2b_kernel(const float* __restrict__ in,
                                                  bf16* __restrict__ out, int n)
{
    int i = blockIdx.x * 256 + threadIdx.x;
    if (i < n) out[i] = __float2bfloat16(in[i]);
}

// ================= folded gate bias, z-batched (blockIdx.x = z) =================
__global__ __launch_bounds__(256) void bias_kernel(
    const float* __restrict__ bv, const float* __restrict__ Wmix, const float* __restrict__ bmix,
    const float* __restrict__ Wg, const float* __restrict__ bg, float* __restrict__ bgconst)
{
    const int z = blockIdx.x;
    const float* bvz = bv + z * 64;
    const float* Wmz = Wmix + z * 12288;
    const float* bmz = bmix + z * 64;
    const float* Wgz = Wg + z * 16384;
    const float* bgz = bg + z * 256;
    float* outb = bgconst + z * 256;
    __shared__ float bconst[64];
    const int tid = threadIdx.x;
    if (tid < 64) {
        float s = bmz[tid];
        for (int kp = 0; kp < 3; ++kp)
            for (int f = 0; f < 64; ++f) s += bvz[f] * Wmz[kp * 4096 + f * 64 + tid];
        bconst[tid] = s;
    }
    __syncthreads();
    int g = tid >> 6, fo = tid & 63;
    float s = bgz[g * 64 + fo];
    for (int e = 0; e < 64; ++e) s += bconst[e] * Wgz[g * 4096 + e * 64 + fo];
    outb[tid] = s;
}

// ====== WbigT[(g*64+f)][q] = sum_e Wvc0[kp][c][e]*Wg0[g][e][f], q=kp*3+c, pad 32 ======
__global__ __launch_bounds__(256) void wbig_kernel(
    const float* __restrict__ Wvc0, const float* __restrict__ Wg0, bf16* __restrict__ WbigT)
{
    const int tid = threadIdx.x;
    const int g = tid >> 6, fo = tid & 63;
    float v[9];
#pragma unroll
    for (int q = 0; q < 9; ++q) {
        const int kp = q / 3, c = q % 3;
        float s = 0.f;
        for (int e = 0; e < 64; ++e)
            s += Wvc0[kp * 192 + c * 64 + e] * Wg0[g * 4096 + e * 64 + fo];
        v[q] = s;
    }
#pragma unroll
    for (int i = 0; i < 32; ++i)
        WbigT[(size_t)tid * 32 + i] = __float2bfloat16(i < 9 ? v[i] : 0.f);
}

// ====== XT[(lglobal*16+b)*3+c][n] = hist[b][l][n][c], bf16 — whole run ======
__global__ __launch_bounds__(256) void xt_build(
    const float* __restrict__ hist, bf16* __restrict__ XT)
{
    __shared__ float xs[3][1024];
    const int lb = blockIdx.x;
    const int l = lb >> 4, b = lb & 15;
    const int tid = threadIdx.x;
    const float* xp = hist + ((size_t)b * L_ + l) * N_ * 3;
    for (int i = tid; i < 3072; i += 256) xs[i % 3][i / 3] = xp[i];
    __syncthreads();
#pragma unroll
    for (int c = 0; c < 3; ++c)
#pragma unroll
        for (int q = 0; q < 4; ++q) {
            int n = q * 256 + tid;
            XT[((size_t)lb * 3 + c) * 1024 + n] = __float2bfloat16(xs[c][n]);
        }
}

__device__ __forceinline__ void gload16(const bf16* g, bf16* l)
{
    __builtin_amdgcn_global_load_lds((const __attribute__((address_space(1))) void*)g,
                                     (__attribute__((address_space(3))) void*)l, 16, 0, 0);
}

// ================= bf16 MFMA GEMM (NT): C = A @ BT^T, 128^2 tile =================
// REMAP=1: layer-1 V scatter (per-lane stores). REMAP=4: same math, LDS-staged
// COALESCED writes (256B runs). REMAP=2: Y scatter. REMAP=3: merged M1/M2.
template <int OUT_BF16, int REMAP>
__global__ __launch_bounds__(256) void gemm_mfma(
    const bf16* __restrict__ A, const bf16* __restrict__ BT, void* __restrict__ Cp,
    int M, int N, int K, int lda, int ldb, int ldc,
    const float* __restrict__ bias, int Nmask)
{
    __shared__ __align__(16) bf16 sh[16384];   // As = sh, Bs = sh+8192; reused as T
    bf16* As = sh;
    bf16* Bs = sh + 8192;
    const int tid = threadIdx.x;
    const int lane = tid & 63, w = tid >> 6;
    const int wr = w >> 1, wc = w & 1;
    const int row0 = blockIdx.y * 128, col0 = blockIdx.x * 128;
    if (REMAP == 1 || REMAP == 4) BT += (size_t)blockIdx.z * 64;
    if (REMAP == 2) A += (size_t)blockIdx.z * 1024;
    if (REMAP == 3) {
        const int z3 = blockIdx.z >> 1, wh = blockIdx.z & 1;
        if (wh) A = BT + (size_t)z3 * 1048576;
        BT = (const bf16*)bias + (size_t)z3 * 1048576;
        Cp = (void*)((bf16*)Cp + (size_t)z3 * 3145728 + (size_t)wh * 1024);
        bias = nullptr;
    }

    f32x4 acc[4][4];
#pragma unroll
    for (int i = 0; i < 4; ++i)
#pragma unroll
        for (int j = 0; j < 4; ++j) acc[i][j] = (f32x4){0.f, 0.f, 0.f, 0.f};

    const int srow = w * 32 + (lane >> 3);
    const int scolsw = ((lane & 7) ^ (lane >> 3)) * 8;

    for (int k0 = 0; k0 < K; k0 += 64) {
#pragma unroll
        for (int i = 0; i < 4; ++i) {
            gload16(A + (size_t)(row0 + srow + i * 8) * lda + k0 + scolsw,
                    &As[(w * 32 + i * 8) * 64]);
            gload16(BT + (size_t)(col0 + srow + i * 8) * ldb + k0 + scolsw,
                    &Bs[(w * 32 + i * 8) * 64]);
        }
        __syncthreads();
#pragma unroll
        for (int kk = 0; kk < 64; kk += 32) {
            s16x8 af[4], bfr[4];
            const int ko = (kk + (lane >> 4) * 8) ^ ((lane & 7) << 3);
#pragma unroll
            for (int mi = 0; mi < 4; ++mi)
                af[mi] = *(const s16x8*)&As[(wr * 64 + mi * 16 + (lane & 15)) * 64 + ko];
#pragma unroll
            for (int ni = 0; ni < 4; ++ni)
                bfr[ni] = *(const s16x8*)&Bs[(wc * 64 + ni * 16 + (lane & 15)) * 64 + ko];
#pragma unroll
            for (int mi = 0; mi < 4; ++mi)
#pragma unroll
                for (int ni = 0; ni < 4; ++ni)
                    acc[mi][ni] = __builtin_amdgcn_mfma_f32_16x16x32_bf16(
                        af[mi], bfr[ni], acc[mi][ni], 0, 0, 0);
        }
        __syncthreads();
    }

    if (REMAP == 4) {
        // stage acc -> sh as T[128 local rows][128 local cols] bf16
        ushort* T = (ushort*)sh;
#pragma unroll
        for (int mi = 0; mi < 4; ++mi)
#pragma unroll
            for (int ni = 0; ni < 4; ++ni)
#pragma unroll
                for (int j = 0; j < 4; ++j) {
                    const int lr = wr * 64 + mi * 16 + (lane >> 4) * 4 + j;
                    const int lc = wc * 64 + ni * 16 + (lane & 15);
                    bf16 h = __float2bfloat16(acc[mi][ni][j]);
                    T[lr * 128 + lc] = *(const ushort*)&h;
                }
        __syncthreads();
        bf16* outb = (bf16*)Cp + (size_t)blockIdx.z * (64 * 3072);
        const uint* Tu = (const uint*)T;
#pragma unroll
        for (int it = 0; it < 32; ++it) {
            const int r = it * 4 + (tid >> 6);
            const int gr = row0 + r;
            if (gr < Nmask) {
                uint v = Tu[r * 64 + (tid & 63)];
                *(uint*)&outb[(size_t)(gr & 63) * 3072 + (gr >> 6) * 1024
                              + col0 + (tid & 63) * 2] = v;
            }
        }
        return;
    }
    if (REMAP == 1) {
        bf16* outb = (bf16*)Cp + (size_t)blockIdx.z * (64 * 3072);
#pragma unroll
        for (int mi = 0; mi < 4; ++mi) {
            const int gr = row0 + wr * 64 + mi * 16 + (lane >> 4) * 4;
#pragma unroll
            for (int ni = 0; ni < 4; ++ni) {
                const int gc = col0 + wc * 64 + ni * 16 + (lane & 15);
#pragma unroll
                for (int j = 0; j < 4; ++j) {
                    const int r = gr + j;
                    if (r >= Nmask) continue;
                    outb[(size_t)(r & 63) * 3072 + (r >> 6) * 1024 + gc] =
                        __float2bfloat16(acc[mi][ni][j]);
                }
            }
        }
        return;
    }
    if (REMAP == 2) {
        bf16* outb = (bf16*)Cp;
        const int kpoff = blockIdx.z * 3;
#pragma unroll
        for (int mi = 0; mi < 4; ++mi) {
            const int gr = row0 + wr * 64 + mi * 16 + (lane >> 4) * 4;
#pragma unroll
            for (int ni = 0; ni < 4; ++ni) {
                const int gc = col0 + wc * 64 + ni * 16 + (lane & 15);
                if (gc >= Nmask) continue;
                const int dstc = (gc / 3) * 32 + kpoff + gc % 3;
#pragma unroll
                for (int j = 0; j < 4; ++j)
                    outb[(size_t)(gr + j) * ldc + dstc] = __float2bfloat16(acc[mi][ni][j]);
            }
        }
        return;
    }

#pragma unroll
    for (int mi = 0; mi < 4; ++mi) {
        const int gr = row0 + wr * 64 + mi * 16 + (lane >> 4) * 4;
#pragma unroll
        for (int ni = 0; ni < 4; ++ni) {
            const int gc = col0 + wc * 64 + ni * 16 + (lane & 15);
            if (gc >= Nmask) continue;
            const float bb = bias ? bias[gc] : 0.f;
#pragma unroll
            for (int j = 0; j < 4; ++j) {
                float v = acc[mi][ni][j] + bb;
                if (OUT_BF16)
                    ((bf16*)Cp)[(size_t)(gr + j) * ldc + gc] = __float2bfloat16(v);
                else
                    ((float*)Cp)[(size_t)(gr + j) * ldc + gc] = v;
            }
        }
    }
}

// ====== 8-phase pipelined bf16 MFMA GEMM (NT), 256x256 tile, BK=64 (r7-validated) ======
__global__ __launch_bounds__(512) void gemm_pipe(
    const bf16* __restrict__ A, const bf16* __restrict__ BT, bf16* __restrict__ C,
    int Nc, int K)
{
    __shared__ __align__(16) bf16 lds[8 * 8192];
    const int tid = threadIdx.x;
    const int lane = tid & 63, w = tid >> 6;
    const int wm = w >> 2, wn = w & 3, bh = wn >> 1;
    const int row0 = blockIdx.y * 256, col0 = blockIdx.x * 256;

    const int strow = tid >> 3;
    const int srck  = ((tid & 7) ^ ((tid >> 3) & 7)) << 3;
    const int e7 = lane & 7, fs = lane >> 4, a15 = lane & 15;

    int aoff0[8], boff0[4];
#pragma unroll
    for (int mi = 0; mi < 8; ++mi)
        aoff0[mi] = (mi * 16 + a15) * 64 + ((fs ^ e7) << 3);
#pragma unroll
    for (int ni = 0; ni < 4; ++ni)
        boff0[ni] = ((wn & 1) * 64 + ni * 16 + a15) * 64 + ((fs ^ e7) << 3);

    auto stage = [&](int mat, int half, int kt) {
        bf16* dst = &lds[(size_t)((((kt & 1) << 1) | mat) * 2 + half) * 8192 + w * 512];
        const bf16* src = (mat ? BT + (size_t)col0 * K : A + (size_t)row0 * K)
                          + (size_t)(half * 128) * K + kt * 64 + srck;
        gload16(src + (size_t)strow * K, dst);
        gload16(src + (size_t)(64 + strow) * K, dst + 4096);
    };

    f32x4 acc[8][4];
#pragma unroll
    for (int i = 0; i < 8; ++i)
#pragma unroll
        for (int j = 0; j < 4; ++j) acc[i][j] = (f32x4){0.f, 0.f, 0.f, 0.f};

    s16x8 b0, b1, b2, b3;

#define MF_(a, mi) { \
    acc[mi][0] = __builtin_amdgcn_mfma_f32_16x16x32_bf16(a, b0, acc[mi][0], 0, 0, 0); \
    acc[mi][1] = __builtin_amdgcn_mfma_f32_16x16x32_bf16(a, b1, acc[mi][1], 0, 0, 0); \
    acc[mi][2] = __builtin_amdgcn_mfma_f32_16x16x32_bf16(a, b2, acc[mi][2], 0, 0, 0); \
    acc[mi][3] = __builtin_amdgcn_mfma_f32_16x16x32_bf16(a, b3, acc[mi][3], 0, 0, 0); }

#define PH_(d, kh, g, DOB, STG) { \
    const bf16* Ab = &lds[((d) * 4 + wm) * 8192]; \
    const bf16* Bb = &lds[((d) * 4 + 2 + bh) * 8192]; \
    if (DOB) { \
        b0 = *(const s16x8*)&Bb[boff0[0] ^ ((kh) * 32)]; \
        b1 = *(const s16x8*)&Bb[boff0[1] ^ ((kh) * 32)]; \
        b2 = *(const s16x8*)&Bb[boff0[2] ^ ((kh) * 32)]; \
        b3 = *(const s16x8*)&Bb[boff0[3] ^ ((kh) * 32)]; \
    } \
    s16x8 a0 = *(const s16x8*)&Ab[aoff0[(g) * 4 + 0] ^ ((kh) * 32)]; \
    s16x8 a1 = *(const s16x8*)&Ab[aoff0[(g) * 4 + 1] ^ ((kh) * 32)]; \
    s16x8 a2 = *(const s16x8*)&Ab[aoff0[(g) * 4 + 2] ^ ((kh) * 32)]; \
    s16x8 a3 = *(const s16x8*)&Ab[aoff0[(g) * 4 + 3] ^ ((kh) * 32)]; \
    STG; \
    __builtin_amdgcn_s_barrier(); \
    asm volatile("s_waitcnt lgkmcnt(0)" ::: "memory"); \
    __builtin_amdgcn_sched_barrier(0); \
    __builtin_amdgcn_s_setprio(1); \
    MF_(a0, (g) * 4 + 0); MF_(a1, (g) * 4 + 1); \
    MF_(a2, (g) * 4 + 2); MF_(a3, (g) * 4 + 3); \
    __builtin_amdgcn_s_setprio(0); \
    __builtin_amdgcn_s_barrier(); }

    const int NT = K >> 6;   // even
    stage(0, 0, 0); stage(0, 1, 0); stage(1, 0, 0); stage(1, 1, 0);
    stage(0, 0, 1);

    for (int i = 0; i < NT / 2; ++i) {
        const int kt = 2 * i;
        asm volatile("s_waitcnt vmcnt(2)" ::: "memory");
        __builtin_amdgcn_sched_barrier(0);
        __builtin_amdgcn_s_barrier();
        PH_(0, 0, 0, 1, { stage(0, 1, kt + 1); });
        PH_(0, 0, 1, 0, { stage(1, 0, kt + 1); });
        PH_(0, 1, 0, 1, { stage(1, 1, kt + 1); });
        PH_(0, 1, 1, 0, { if (kt + 2 < NT) stage(0, 0, kt + 2); });
        if (kt + 2 < NT) { asm volatile("s_waitcnt vmcnt(2)" ::: "memory"); }
        else             { asm volatile("s_waitcnt vmcnt(0)" ::: "memory"); }
        __builtin_amdgcn_sched_barrier(0);
        __builtin_amdgcn_s_barrier();
        PH_(1, 0, 0, 1, { if (kt + 2 < NT) stage(0, 1, kt + 2); });
        PH_(1, 0, 1, 0, { if (kt + 2 < NT) stage(1, 0, kt + 2); });
        PH_(1, 1, 0, 1, { if (kt + 2 < NT) stage(1, 1, kt + 2); });
        PH_(1, 1, 1, 0, { if (kt + 3 < NT) stage(0, 0, kt + 3); });
    }
#undef PH_
#undef MF_

#pragma unroll
    for (int mi = 0; mi < 8; ++mi) {
        const int gr = row0 + wm * 128 + mi * 16 + (lane >> 4) * 4;
#pragma unroll
        for (int ni = 0; ni < 4; ++ni) {
            const int gc = col0 + wn * 64 + ni * 16 + (lane & 15);
#pragma unroll
            for (int j = 0; j < 4; ++j)
                C[(size_t)(gr + j) * Nc + gc] = __float2bfloat16(acc[mi][ni][j]);
        }
    }
}

// ========== layer-1: fused gates GEMM (K=64) + IN-REGISTER LSTM scan ==========
__global__ __launch_bounds__(256, 4) void fused_gates_scan(
    const bf16* __restrict__ HG, const bf16* __restrict__ WgcT,
    const float* __restrict__ bgc, float* __restrict__ ct_buf,
    bf16* __restrict__ ht_out, float* __restrict__ htlast,
    int LC, int l0, int initct)
{
    __shared__ __align__(16) bf16 Bs[256 * 64];
    __shared__ float bgs[256];
    const int tid = threadIdx.x;
    const int lane = tid & 63, w = tid >> 6;
    const int n = blockIdx.x;
    const int swz = ((lane & 7) ^ (lane >> 3)) * 8;
    const int l8 = (lane >> 3) * 64;

#pragma unroll
    for (int r = 0; r < 8; ++r)
        gload16(WgcT + r * 2048 + w * 512 + l8 + swz, &Bs[r * 2048 + w * 512]);
    bgs[tid] = bgc[tid];
    __syncthreads();

    const int ar = lane & 15;
    const int ak = (lane >> 4) * 8;
    const int kswz = (lane & 7) << 3;
    const int f = w * 16 + ar;
    const int r0 = (lane >> 4) * 4;
    const float bgf = bgs[f], bgi = bgs[64 + f], bgg = bgs[128 + f], bgo = bgs[192 + f];

    float ct[4];
    const size_t cbase = (size_t)n * 1024;
#pragma unroll
    for (int j = 0; j < 4; ++j)
        ct[j] = initct ? 0.f : ct_buf[cbase + (size_t)(r0 + j) * 64 + f];

    const bf16* HGn = HG + (size_t)n * LC * 1024;
    s16x8 a0 = *(const s16x8*)&HGn[ar * 64 + ak];
    s16x8 a1 = *(const s16x8*)&HGn[ar * 64 + ak + 32];

    for (int l = 0; l < LC; ++l) {
        s16x8 p0 = a0, p1 = a1;
        if (l + 1 < LC) {
            p0 = *(const s16x8*)&HGn[((l + 1) * 16 + ar) * 64 + ak];
            p1 = *(const s16x8*)&HGn[((l + 1) * 16 + ar) * 64 + ak + 32];
        }
        f32x4 acc[4];
#pragma unroll
        for (int ni = 0; ni < 4; ++ni) acc[ni] = (f32x4){0.f, 0.f, 0.f, 0.f};
#pragma unroll
        for (int ni = 0; ni < 4; ++ni) {
            s16x8 bf = *(const s16x8*)&Bs[(ni * 64 + w * 16 + ar) * 64 + (ak ^ kswz)];
            acc[ni] = __builtin_amdgcn_mfma_f32_16x16x32_bf16(a0, bf, acc[ni], 0, 0, 0);
        }
#pragma unroll
        for (int ni = 0; ni < 4; ++ni) {
            s16x8 bf = *(const s16x8*)&Bs[(ni * 64 + w * 16 + ar) * 64 + ((ak + 32) ^ kswz)];
            acc[ni] = __builtin_amdgcn_mfma_f32_16x16x32_bf16(a1, bf, acc[ni], 0, 0, 0);
        }
        const size_t hbase = ((size_t)n * LC + l) * 1024;
        const bool last = (l0 + l == L_ - 1);
#pragma unroll
        for (int j = 0; j < 4; ++j) {
            float xf = acc[0][j] + bgf;
            float xi = acc[1][j] + bgi;
            float xg = acc[2][j] + bgg;
            float xo = acc[3][j] + bgo;
            float fg = 1.f / (1.f + __expf(-xf));
            float ig = 1.f / (1.f + __expf(-xi));
            float gg = 2.f / (1.f + __expf(-2.f * xg)) - 1.f;
            float og = 1.f / (1.f + __expf(-xo));
            ct[j] = fg * ct[j] + ig * gg;
            float ht = og * (2.f / (1.f + __expf(-2.f * ct[j])) - 1.f);
            if (ht_out) ht_out[hbase + (size_t)(r0 + j) * 64 + f] = __float2bfloat16(ht);
            if (htlast && last) htlast[cbase + (size_t)(r0 + j) * 64 + f] = ht;
        }
        a0 = p0; a1 = p1;
    }
#pragma unroll
    for (int j = 0; j < 4; ++j)
        ct_buf[cbase + (size_t)(r0 + j) * 64 + f] = ct[j];
}

// ========== layer-0: gates from Y (K=32, rank-9) + IN-REGISTER LSTM scan ==========
__global__ __launch_bounds__(256, 4) void fused_gates_scan_y(
    const bf16* __restrict__ Y, const bf16* __restrict__ WbigT,
    const float* __restrict__ bgc, float* __restrict__ ct_buf,
    bf16* __restrict__ ht_out, float* __restrict__ htlast,
    int LC, int l0, int initct)
{
    __shared__ bf16 Bs2[256 * 40];
    __shared__ float bgs[256];
    const int tid = threadIdx.x;
    const int lane = tid & 63, w = tid >> 6;
    const int n = blockIdx.x;
    {
        const uint4* src = (const uint4*)(WbigT + (size_t)tid * 32);
        uint4* dst = (uint4*)&Bs2[tid * 40];
        dst[0] = src[0]; dst[1] = src[1]; dst[2] = src[2]; dst[3] = src[3];
    }
    bgs[tid] = bgc[tid];
    __syncthreads();

    const int ar = lane & 15, fs = lane >> 4;
    const int f = w * 16 + ar;
    const int r0 = fs * 4;
    const float bgf = bgs[f], bgi = bgs[64 + f], bgg = bgs[128 + f], bgo = bgs[192 + f];

    float ct[4];
    const size_t cbase = (size_t)n * 1024;
#pragma unroll
    for (int j = 0; j < 4; ++j)
        ct[j] = initct ? 0.f : ct_buf[cbase + (size_t)(r0 + j) * 64 + f];

    const bf16* Yn = Y + (size_t)n * LC * 512;
    s16x8 a = *(const s16x8*)&Yn[ar * 32 + fs * 8];

    for (int l = 0; l < LC; ++l) {
        s16x8 p = a;
        if (l + 1 < LC) p = *(const s16x8*)&Yn[((l + 1) * 16 + ar) * 32 + fs * 8];
        f32x4 acc[4];
#pragma unroll
        for (int ni = 0; ni < 4; ++ni) {
            s16x8 bf = *(const s16x8*)&Bs2[(ni * 64 + w * 16 + ar) * 40 + fs * 8];
            acc[ni] = __builtin_amdgcn_mfma_f32_16x16x32_bf16(
                a, bf, (f32x4){0.f, 0.f, 0.f, 0.f}, 0, 0, 0);
        }
        const size_t hbase = ((size_t)n * LC + l) * 1024;
        const bool last = (l0 + l == L_ - 1);
#pragma unroll
        for (int j = 0; j < 4; ++j) {
            float xf = acc[0][j] + bgf;
            float xi = acc[1][j] + bgi;
            float xg = acc[2][j] + bgg;
            float xo = acc[3][j] + bgo;
            float fg = 1.f / (1.f + __expf(-xf));
            float ig = 1.f / (1.f + __expf(-xi));
            float gg = 2.f / (1.f + __expf(-2.f * xg)) - 1.f;
            float og = 1.f / (1.f + __expf(-xo));
            ct[j] = fg * ct[j] + ig * gg;
            float ht = og * (2.f / (1.f + __expf(-2.f * ct[j])) - 1.f);
            if (ht_out) ht_out[hbase + (size_t)(r0 + j) * 64 + f] = __float2bfloat16(ht);
            if (htlast && last) htlast[cbase + (size_t)(r0 + j) * 64 + f] = ht;
        }
        a = p;
    }
#pragma unroll
    for (int j = 0; j < 4; ++j)
        ct_buf[cbase + (size_t)(r0 + j) * 64 + f] = ct[j];
}

// ================= decoder =================
__global__ __launch_bounds__(256) void decoder_kernel(
    const float* __restrict__ h0, const float* __restrict__ h1,
    const float* __restrict__ Wdec, const float* __restrict__ bdec,
    const float* __restrict__ Wout, const float* __restrict__ bout,
    float* __restrict__ outp)
{
    __shared__ float Wd[12 * 2 * 64];
    __shared__ float Wo[144];
    __shared__ float bd[12], bo[12];
    const int tid = threadIdx.x;
    for (int i = tid; i < 12 * 2 * 64; i += 256) Wd[i] = Wdec[i];
    for (int i = tid; i < 144; i += 256) Wo[i] = Wout[i];
    if (tid < 12) { bd[tid] = bdec[tid]; bo[tid] = bout[tid]; }
    __syncthreads();
    const int gid = blockIdx.x * 256 + tid;   // b*1024 + n
    const int b = gid >> 10, n = gid & 1023;
    const float* h0r = h0 + ((size_t)n * 16 + b) * 64;
    const float* h1r = h1 + ((size_t)n * 16 + b) * 64;
    float dec[12];
#pragma unroll
    for (int o = 0; o < 12; ++o) dec[o] = bd[o];
    for (int e = 0; e < 64; ++e) {
        float v0 = h0r[e], v1 = h1r[e];
#pragma unroll
        for (int o = 0; o < 12; ++o) dec[o] += v0 * Wd[o * 128 + e] + v1 * Wd[o * 128 + 64 + e];
    }
#pragma unroll
    for (int o = 0; o < 12; ++o) {
        float s = bo[o];
#pragma unroll
        for (int p = 0; p < 12; ++p) s += Wo[o * 12 + p] * dec[p];
        outp[((size_t)b * 12 + o) * 1024 + n] = s;
    }
}

extern "C" void kernel_launch(void* const* d_in, const int* in_sizes, int n_in,
                              void* d_out, int out_size, void* d_ws, size_t ws_size,
                              hipStream_t stream)
{
    const float* hist = (const float*)d_in[0];
    const float* adj  = (const float*)d_in[1];
    const float* Wv0  = (const float*)d_in[2];
    const float* Wv1  = (const float*)d_in[3];
    const float* bv   = (const float*)d_in[4];
    const float* E    = (const float*)d_in[5];
    const float* Wq   = (const float*)d_in[6];
    const float* Wk   = (const float*)d_in[7];
    const float* Eg1  = (const float*)d_in[8];
    const float* Eg2  = (const float*)d_in[9];
    const float* Wmix = (const float*)d_in[10];
    const float* bmix = (const float*)d_in[11];
    const float* Wg   = (const float*)d_in[12];
    const float* bg   = (const float*)d_in[13];
    const float* Wdec = (const float*)d_in[14];
    const float* bdec = (const float*)d_in[15];
    const float* Wout = (const float*)d_in[16];
    const float* bout = (const float*)d_in[17];
    float* outp = (float*)d_out;
    (void)in_sizes; (void)n_in; (void)out_size;

    char* ws = (char*)d_ws;
    size_t off = 0;
    auto alloc = [&](size_t bytes) -> void* {
        void* p = (void*)(ws + off);
        off += (bytes + 255) & ~(size_t)255;
        return p;
    };
    bf16*  Mcatb  = (bf16*)alloc((size_t)2 * 1024 * 3072 * 2);
    bf16*  attnT2 = (bf16*)alloc((size_t)2 * 1024 * 1024 * 2);
    bf16*  adjb   = (bf16*)alloc((size_t)1024 * 1024 * 2);
    bf16*  adpb2  = (bf16*)alloc((size_t)2 * 1024 * 1024 * 2);
    float* qkb    = (float*)alloc((size_t)4 * 1024 * 64 * 4);
    float* logit2 = (float*)alloc((size_t)2 * 1024 * 1024 * 4);
    float* WvcAll = (float*)alloc((size_t)(640 + 12288) * 4);   // Wvc0 @0, Wvc1 @640
    bf16*  Wvc1T  = (bf16*)alloc(256 * 64 * 2);
    bf16*  WgcT1  = (bf16*)alloc(256 * 64 * 2);
    bf16*  WbigT  = (bf16*)alloc(256 * 32 * 2);
    float* bgc01  = (float*)alloc(2 * 256 * 4);                 // bgc0 @0, bgc1 @256
    float* ct0    = (float*)alloc((size_t)N_ * B_ * 64 * 4);
    float* ct1    = (float*)alloc((size_t)N_ * B_ * 64 * 4);
    float* hl0    = (float*)alloc((size_t)N_ * B_ * 64 * 4);
    float* hl1    = (float*)alloc((size_t)N_ * B_ * 64 * 4);
    bf16*  XT     = (bf16*)alloc((size_t)L_ * 16 * 3 * 1024 * 2);
    size_t fixed = off;
    float* Wvc0 = WvcAll;
    float* Wvc1 = WvcAll + 640;

    // ---- plan selection by workspace size ----
    const size_t YALL_B = (size_t)1024 * L_ * 16 * 32 * 2;   // 96MB
    const size_t HT_B   = (size_t)1024 * L_ * 16 * 64 * 2;   // 192MB
    const size_t GUARD  = 1 << 20;
    int plan;  int LC;
    if (fixed + YALL_B + HT_B + (size_t)16 * 6291456ull + HT_B + GUARD <= ws_size) {
        plan = 0; LC = 16;
    } else if (fixed + YALL_B + HT_B + (size_t)16 * 6291456ull
               + (size_t)16 * 2097152ull + GUARD <= ws_size) {
        plan = 1; LC = 16;
    } else if (fixed + (size_t)16 * 9437184ull + GUARD <= ws_size) {
        plan = 2; LC = 16;
    } else {
        plan = 2; LC = 8;
    }

    bf16 *Yall = nullptr, *ht0 = nullptr, *VcatT = nullptr, *HG = nullptr, *Ychunk = nullptr;
    if (plan <= 1) {
        Yall  = (bf16*)alloc(YALL_B);
        ht0   = (bf16*)alloc(HT_B);
        VcatT = (bf16*)alloc((size_t)LC * 6291456ull);
        HG    = (bf16*)alloc(plan == 0 ? HT_B : (size_t)LC * 2097152ull);
    } else {
        VcatT  = (bf16*)alloc((size_t)LC * 6291456ull);
        HG     = (bf16*)alloc((size_t)LC * 2097152ull);
        Ychunk = (bf16*)alloc((size_t)LC * 1048576ull);
    }

    dim3 blk(256);
    dim3 blk512(512);
    bf16*  McatB[2] = {Mcatb, Mcatb + 3145728};

    // -------- setup, z-batched --------
    f2b_kernel<<<4096, blk, 0, stream>>>(adj, adjb, 1024 * 1024);
    gemm_nn<1><<<dim3(1, 16, 4), blk, 0, stream>>>(E, Wq, qkb,
        1024, 64, 64, 64, 64, 64, (const float*)Wk);
    gemm_nt<<<dim3(16, 16, 2), blk, 0, stream>>>(qkb, qkb + 65536, logit2,
        1024, 64, 0.125f, 131072, 131072, 1048576);
    row_softmax<<<dim3(1024, 2), blk, 0, stream>>>(logit2, logit2, 1024,
        Mcatb + 2048, 3072, 1048576, 3145728, 0);
    transpose_f2b<<<dim3(16, 16, 2), blk, 0, stream>>>(logit2, attnT2);
    gemm_nt<<<dim3(16, 16, 2), blk, 0, stream>>>(Eg1, Eg2, logit2,
        1024, 16, 1.f, 16384, 16384, 1048576);
    row_softmax<<<dim3(1024, 2), blk, 0, stream>>>(logit2, nullptr, 0,
        adpb2, 1024, 1048576, 1048576, 1);
    // merged tiny weight GEMMs (6 in one launch)
    gemm_nn<2><<<dim3(1, 1, 6), blk, 0, stream>>>(Wv0, Wmix, WvcAll,
        0, 64, 64, 64, 64, 64, (const float*)Wv1);
    wbig_kernel<<<1, blk, 0, stream>>>(Wvc0, Wg, WbigT);
    wvc1t_kernel<<<64, blk, 0, stream>>>(Wvc1, Wvc1T);
    wgct_kernel<<<64, blk, 0, stream>>>(Wg + 16384, WgcT1);
    bias_kernel<<<2, blk, 0, stream>>>(bv, Wmix, bmix, Wg, bg, bgc01);
    gemm_mfma<1, 3><<<dim3(8, 8, 4), blk, 0, stream>>>(adjb, adpb2, Mcatb,
        1024, 1024, 1024, 1024, 1024, 3072, (const float*)attnT2, 1024);

    xt_build<<<L_ * 16, blk, 0, stream>>>(hist, XT);

    if (plan <= 1) {
        hipMemsetAsync(Yall, 0, YALL_B, stream);
        gemm_mfma<1, 2><<<dim3(L_ * 48 / 128, 8, 3), blk, 0, stream>>>(McatB[0],
            XT, Yall, 1024, L_ * 48, 1024, 3072, 1024, L_ * 512, nullptr, L_ * 48);
        fused_gates_scan_y<<<1024, blk, 0, stream>>>(Yall, WbigT, bgc01, ct0,
            ht0, hl0, L_, 0, 1);
        const int nch = L_ / LC;
        for (int c = 0; c < nch; ++c) {
            const int l0 = c * LC;
            gemm_mfma<1, 4><<<dim3(8, 2, LC * 16), blk, 0, stream>>>(Wvc1T,
                ht0 + (size_t)l0 * 1024, VcatT,
                256, 1024, 64, 64, L_ * 1024, 0, nullptr, 192);
            if (plan == 0) {
                gemm_pipe<<<dim3(LC * 4, 4), blk512, 0, stream>>>(McatB[1], VcatT,
                    HG + (size_t)l0 * 1024, L_ * 1024, 3072);
            } else {
                gemm_pipe<<<dim3(LC * 4, 4), blk512, 0, stream>>>(McatB[1], VcatT,
                    HG, LC * 1024, 3072);
                fused_gates_scan<<<1024, blk, 0, stream>>>(HG, WgcT1, bgc01 + 256, ct1,
                    nullptr, hl1, LC, l0, c == 0);
            }
        }
        if (plan == 0)
            fused_gates_scan<<<1024, blk, 0, stream>>>(HG, WgcT1, bgc01 + 256, ct1,
                nullptr, hl1, L_, 0, 1);
    } else {
        hipMemsetAsync(Ychunk, 0, (size_t)LC * 1048576ull, stream);
        const int nch = L_ / LC;
        for (int c = 0; c < nch; ++c) {
            const int l0 = c * LC;
            gemm_mfma<1, 2><<<dim3(LC * 48 / 128, 8, 3), blk, 0, stream>>>(McatB[0],
                XT + (size_t)l0 * 49152, Ychunk,
                1024, LC * 48, 1024, 3072, 1024, LC * 512, nullptr, LC * 48);
            fused_gates_scan_y<<<1024, blk, 0, stream>>>(Ychunk, WbigT, bgc01, ct0,
                HG, hl0, LC, l0, c == 0);
            gemm_mfma<1, 4><<<dim3(8, 2, LC * 16), blk, 0, stream>>>(Wvc1T, HG, VcatT,
                256, 1024, 64, 64, LC * 1024, 0, nullptr, 192);
            gemm_pipe<<<dim3(LC * 4, 4), blk512, 0, stream>>>(McatB[1], VcatT, HG,
                LC * 1024, 3072);
            fused_gates_scan<<<1024, blk, 0, stream>>>(HG, WgcT1, bgc01 + 256, ct1,
                nullptr, hl1, LC, l0, c == 0);
        }
    }
    decoder_kernel<<<64, blk, 0, stream>>>(hl0, hl1, Wdec, bdec, Wout, bout, outp);
}